// Round 6
// baseline (61.715 us; speedup 1.0000x reference)
//
#include <hip/hip_runtime.h>

#define NE 8              // experts
#define H4 512            // float4 per token row (2048 floats)
#define NTOK 16384        // 4 * 4096 tokens
#define TPW 4             // tokens per wave
#define WPB 8             // waves per block (512 threads)
#define TPB (TPW * WPB)   // 32 tokens per block
#define KC 8              // K-steps
#define C4 64             // float4 per chunk per row (1 KB)
#define GATE4 (NE * H4)   // 4096 float4 = 64 KB gate
#define AUX_COEF 0.01f

typedef const __attribute__((address_space(1))) void* gas_ptr;
typedef __attribute__((address_space(3))) void* lds_ptr;

// Gate lives in LDS (staged once per block) so the ONLY VMEM ops in the loop
// are the 4 global_load_lds stages -> vmcnt(4) is exact and robust. Last
// chunk peeled with vmcnt(0). No __syncthreads in the loop (each wave owns
// its 4 LDS rows). 128 KB dynamic LDS -> 1 block/CU, 8 waves.
__global__ __launch_bounds__(512)
void router_main(const float* __restrict__ hs, const float* __restrict__ gw,
                 float* __restrict__ out, float* __restrict__ ws)
{
    extern __shared__ float4 smem[];      // [GATE4] gate | [2][TPB][C4] h
    float4* gateL = smem;
    float4* hbuf  = smem + GATE4;
    __shared__ float s_psum[NE], s_cnt[NE];

    const int tid = threadIdx.x;
    if (tid < NE) { s_psum[tid] = 0.f; s_cnt[tid] = 0.f; }

    const float4* __restrict__ hs4 = (const float4*)hs;
    const float4* __restrict__ gw4 = (const float4*)gw;

    // stage gate -> LDS once: 4096 float4 / 512 threads = 8 each
    #pragma unroll
    for (int i = 0; i < GATE4 / 512; ++i)
        gateL[tid + i * 512] = gw4[tid + i * 512];
    __syncthreads();

    const int wave = tid >> 6, lane = tid & 63;
    const int tok0 = blockIdx.x * TPB + wave * TPW;
    const int wrow = wave * TPW;          // this wave's LDS row base

    float acc[TPW][NE];
    #pragma unroll
    for (int r = 0; r < TPW; ++r)
        #pragma unroll
        for (int e = 0; e < NE; ++e) acc[r][e] = 0.f;

    // stage(0)
    #pragma unroll
    for (int r = 0; r < TPW; ++r)
        __builtin_amdgcn_global_load_lds(
            (gas_ptr)(hs4 + (size_t)(tok0 + r) * H4 + lane),
            (lds_ptr)&hbuf[(wrow + r) * C4], 16, 0, 0);

    // kc = 0..6: issue stage(kc+1) [4 ops], vmcnt(4) retires stage(kc)
    #pragma unroll
    for (int kc = 0; kc < KC - 1; ++kc) {
        const int kn = kc + 1;
        #pragma unroll
        for (int r = 0; r < TPW; ++r)
            __builtin_amdgcn_global_load_lds(
                (gas_ptr)(hs4 + (size_t)(tok0 + r) * H4 + kn * C4 + lane),
                (lds_ptr)&hbuf[((kn & 1) * TPB + wrow + r) * C4], 16, 0, 0);
        asm volatile("s_waitcnt vmcnt(4)" ::: "memory");
        // gate slice for this chunk (LDS, conflict-free b128)
        float4 g[NE];
        #pragma unroll
        for (int e = 0; e < NE; ++e) g[e] = gateL[e * H4 + kc * C4 + lane];
        #pragma unroll
        for (int r = 0; r < TPW; ++r) {
            const float4 h = hbuf[((kc & 1) * TPB + wrow + r) * C4 + lane];
            #pragma unroll
            for (int e = 0; e < NE; ++e)
                acc[r][e] += h.x * g[e].x + h.y * g[e].y
                           + h.z * g[e].z + h.w * g[e].w;
        }
    }

    // peeled last chunk: drain the one outstanding stage, then compute
    asm volatile("s_waitcnt vmcnt(0)" ::: "memory");
    {
        float4 g[NE];
        #pragma unroll
        for (int e = 0; e < NE; ++e)
            g[e] = gateL[e * H4 + (KC - 1) * C4 + lane];
        #pragma unroll
        for (int r = 0; r < TPW; ++r) {
            const float4 h = hbuf[(((KC - 1) & 1) * TPB + wrow + r) * C4 + lane];
            #pragma unroll
            for (int e = 0; e < NE; ++e)
                acc[r][e] += h.x * g[e].x + h.y * g[e].y
                           + h.z * g[e].z + h.w * g[e].w;
        }
    }

    // full-wave butterfly: every lane ends with complete dots for all 4 tokens
    #pragma unroll
    for (int r = 0; r < TPW; ++r) {
        #pragma unroll
        for (int e = 0; e < NE; ++e) {
            float v = acc[r][e];
            #pragma unroll
            for (int s = 32; s > 0; s >>= 1) v += __shfl_xor(v, s, 64);
            acc[r][e] = v;
        }
    }

    // lane (mod 4) picks its token — static indexing only
    const int ls = lane & 3;
    float lg[NE];
    #pragma unroll
    for (int e = 0; e < NE; ++e)
        lg[e] = (ls == 0) ? acc[0][e] : (ls == 1) ? acc[1][e]
              : (ls == 2) ? acc[2][e] : acc[3][e];

    float m = lg[0];
    #pragma unroll
    for (int e = 1; e < NE; ++e) m = fmaxf(m, lg[e]);
    float p[NE];
    float s = 0.f;
    #pragma unroll
    for (int e = 0; e < NE; ++e) { p[e] = __expf(lg[e] - m); s += p[e]; }
    const float inv = 1.f / s;

    // top-2 on probs; strict '>' keeps lowest index on ties (lax.top_k order)
    float v0 = -1.f; int i0 = 0;
    #pragma unroll
    for (int e = 0; e < NE; ++e) { if (p[e] > v0) { v0 = p[e]; i0 = e; } }
    float v1 = -1.f; int i1 = 0;
    #pragma unroll
    for (int e = 0; e < NE; ++e) { if (e != i0 && p[e] > v1) { v1 = p[e]; i1 = e; } }

    if (lane < TPW) {
        const int tok = tok0 + ls;
        const float wsum = v0 + v1;
        out[tok * 2 + 0] = v0 / wsum;
        out[tok * 2 + 1] = v1 / wsum;
        out[2 * NTOK + tok * 2 + 0] = (float)i0;
        out[2 * NTOK + tok * 2 + 1] = (float)i1;
        #pragma unroll
        for (int e = 0; e < NE; ++e) atomicAdd(&s_psum[e], p[e] * inv);
        atomicAdd(&s_cnt[i0], 1.f);
        atomicAdd(&s_cnt[i1], 1.f);
    }

    __syncthreads();
    if (tid < NE) {
        atomicAdd(&ws[tid], s_psum[tid]);
        atomicAdd(&ws[NE + tid], s_cnt[tid]);
    }
}

// aux = E * sum(expert_frac * router_frac) * coef
__global__ void router_aux(const float* __restrict__ ws, float* __restrict__ out)
{
    if (threadIdx.x == 0 && blockIdx.x == 0) {
        float s = 0.f;
        #pragma unroll
        for (int e = 0; e < NE; ++e) {
            const float ef = ws[NE + e] / (float)(NTOK * 2);
            const float rf = ws[e] / (float)NTOK;
            s += ef * rf;
        }
        out[4 * NTOK] = (float)NE * s * AUX_COEF;
    }
}

extern "C" void kernel_launch(void* const* d_in, const int* in_sizes, int n_in,
                              void* d_out, int out_size, void* d_ws, size_t ws_size,
                              hipStream_t stream)
{
    const float* hs = (const float*)d_in[0];   // [4,4096,2048] f32
    const float* gw = (const float*)d_in[1];   // [8,2048] f32
    float* out = (float*)d_out;                // 32768 rw | 32768 idx | 1 aux
    float* ws  = (float*)d_ws;                 // 16 floats of accumulators

    const size_t lds_bytes = (GATE4 + 2 * TPB * C4) * sizeof(float4); // 128 KB
    hipMemsetAsync(d_ws, 0, 2 * NE * sizeof(float), stream);
    hipLaunchKernelGGL(router_main, dim3(NTOK / TPB), dim3(512), lds_bytes,
                       stream, hs, gw, out, ws);
    hipLaunchKernelGGL(router_aux, dim3(1), dim3(64), 0, stream, ws, out);
}

// Round 7
// 57.360 us; speedup vs baseline: 1.0759x; 1.0759x over previous
//
#include <hip/hip_runtime.h>

#define NE 8              // experts
#define H4 512            // float4 per token row (2048 floats)
#define NTOK 16384        // 4 * 4096 tokens
#define TPW 4             // tokens per wave
#define WPB 8             // waves per block (512 threads)
#define TPB (TPW * WPB)   // 32 tokens per block
#define KC 8              // K-steps
#define C4 64             // float4 per chunk per row (1 KB)
#define NBUF 3            // triple buffer -> prefetch distance 2
#define GATE4 (NE * H4)   // 4096 float4 = 64 KB gate
#define AUX_COEF 0.01f
#define CPOL_NT 2         // GFX940+ CPol: SC0=1, NT=2, SC1=16

typedef const __attribute__((address_space(1))) void* gas_ptr;
typedef __attribute__((address_space(3))) void* lds_ptr;

// Gate in LDS (staged once); h triple-buffered via global_load_lds with NT
// cache policy. Loop VMEM = 4 stage ops/iter only -> counted vmcnt is exact:
// at top of iter kc two stages (kc,kc+1)=8 ops are outstanding; issue
// stage(kc+2) (12), wait vmcnt(8) retires exactly stage(kc). Distance-2
// prefetch: the waited-on load is ~2 iteration-periods old (self-balancing).
// LDS: 64 KB gate + 3*32 KB h = 160 KB, 1 block/CU. Aux accumulators reuse
// the gate region after a post-loop barrier (no static __shared__).
__global__ __launch_bounds__(512)
void router_main(const float* __restrict__ hs, const float* __restrict__ gw,
                 float* __restrict__ out, float* __restrict__ ws)
{
    extern __shared__ float4 smem[];      // [GATE4] gate | [NBUF][TPB][C4] h
    float4* gateL = smem;
    float4* hbuf  = smem + GATE4;
    float*  auxL  = (float*)smem;         // reused AFTER the K-loop + barrier

    const int tid = threadIdx.x;
    const float4* __restrict__ hs4 = (const float4*)hs;
    const float4* __restrict__ gw4 = (const float4*)gw;

    // stage gate -> LDS once: 4096 float4 / 512 threads = 8 each
    #pragma unroll
    for (int i = 0; i < GATE4 / 512; ++i)
        gateL[tid + i * 512] = gw4[tid + i * 512];
    __syncthreads();

    const int wave = tid >> 6, lane = tid & 63;
    const int tok0 = blockIdx.x * TPB + wave * TPW;
    const int wrow = wave * TPW;          // this wave's LDS row base

    float acc[TPW][NE];
    #pragma unroll
    for (int r = 0; r < TPW; ++r)
        #pragma unroll
        for (int e = 0; e < NE; ++e) acc[r][e] = 0.f;

    // prologue: stage chunks 0 and 1 (8 ops outstanding)
    #pragma unroll
    for (int k = 0; k < 2; ++k)
        #pragma unroll
        for (int r = 0; r < TPW; ++r)
            __builtin_amdgcn_global_load_lds(
                (gas_ptr)(hs4 + (size_t)(tok0 + r) * H4 + k * C4 + lane),
                (lds_ptr)&hbuf[(k * TPB + wrow + r) * C4], 16, 0, CPOL_NT);

    // kc = 0..5: issue stage(kc+2), vmcnt(8) retires stage(kc), compute kc
    #pragma unroll
    for (int kc = 0; kc < KC - 2; ++kc) {
        const int kn = kc + 2;
        #pragma unroll
        for (int r = 0; r < TPW; ++r)
            __builtin_amdgcn_global_load_lds(
                (gas_ptr)(hs4 + (size_t)(tok0 + r) * H4 + kn * C4 + lane),
                (lds_ptr)&hbuf[((kn % NBUF) * TPB + wrow + r) * C4], 16, 0, CPOL_NT);
        asm volatile("s_waitcnt vmcnt(8)" ::: "memory");
        float4 g[NE];
        #pragma unroll
        for (int e = 0; e < NE; ++e) g[e] = gateL[e * H4 + kc * C4 + lane];
        #pragma unroll
        for (int r = 0; r < TPW; ++r) {
            const float4 h = hbuf[((kc % NBUF) * TPB + wrow + r) * C4 + lane];
            #pragma unroll
            for (int e = 0; e < NE; ++e)
                acc[r][e] += h.x * g[e].x + h.y * g[e].y
                           + h.z * g[e].z + h.w * g[e].w;
        }
    }

    // peeled kc = 6: no new issue; vmcnt(4) retires stage(6)
    asm volatile("s_waitcnt vmcnt(4)" ::: "memory");
    {
        const int kc = KC - 2;
        float4 g[NE];
        #pragma unroll
        for (int e = 0; e < NE; ++e) g[e] = gateL[e * H4 + kc * C4 + lane];
        #pragma unroll
        for (int r = 0; r < TPW; ++r) {
            const float4 h = hbuf[((kc % NBUF) * TPB + wrow + r) * C4 + lane];
            #pragma unroll
            for (int e = 0; e < NE; ++e)
                acc[r][e] += h.x * g[e].x + h.y * g[e].y
                           + h.z * g[e].z + h.w * g[e].w;
        }
    }

    // peeled kc = 7: full drain
    asm volatile("s_waitcnt vmcnt(0)" ::: "memory");
    {
        const int kc = KC - 1;
        float4 g[NE];
        #pragma unroll
        for (int e = 0; e < NE; ++e) g[e] = gateL[e * H4 + kc * C4 + lane];
        #pragma unroll
        for (int r = 0; r < TPW; ++r) {
            const float4 h = hbuf[((kc % NBUF) * TPB + wrow + r) * C4 + lane];
            #pragma unroll
            for (int e = 0; e < NE; ++e)
                acc[r][e] += h.x * g[e].x + h.y * g[e].y
                           + h.z * g[e].z + h.w * g[e].w;
        }
    }

    // full-wave butterfly: every lane ends with complete dots for all 4 tokens
    #pragma unroll
    for (int r = 0; r < TPW; ++r) {
        #pragma unroll
        for (int e = 0; e < NE; ++e) {
            float v = acc[r][e];
            #pragma unroll
            for (int s = 32; s > 0; s >>= 1) v += __shfl_xor(v, s, 64);
            acc[r][e] = v;
        }
    }

    // lane (mod 4) picks its token — static indexing only
    const int ls = lane & 3;
    float lg[NE];
    #pragma unroll
    for (int e = 0; e < NE; ++e)
        lg[e] = (ls == 0) ? acc[0][e] : (ls == 1) ? acc[1][e]
              : (ls == 2) ? acc[2][e] : acc[3][e];

    float m = lg[0];
    #pragma unroll
    for (int e = 1; e < NE; ++e) m = fmaxf(m, lg[e]);
    float p[NE];
    float s = 0.f;
    #pragma unroll
    for (int e = 0; e < NE; ++e) { p[e] = __expf(lg[e] - m); s += p[e]; }
    const float inv = 1.f / s;

    // top-2 on probs; strict '>' keeps lowest index on ties (lax.top_k order)
    float v0 = -1.f; int i0 = 0;
    #pragma unroll
    for (int e = 0; e < NE; ++e) { if (p[e] > v0) { v0 = p[e]; i0 = e; } }
    float v1 = -1.f; int i1 = 0;
    #pragma unroll
    for (int e = 0; e < NE; ++e) { if (e != i0 && p[e] > v1) { v1 = p[e]; i1 = e; } }

    // aux accumulators reuse gate LDS — all waves are past their last gate
    // read only after this barrier
    __syncthreads();
    if (tid < 2 * NE) auxL[tid] = 0.f;
    __syncthreads();

    if (lane < TPW) {
        const int tok = tok0 + ls;
        const float wsum = v0 + v1;
        out[tok * 2 + 0] = v0 / wsum;
        out[tok * 2 + 1] = v1 / wsum;
        out[2 * NTOK + tok * 2 + 0] = (float)i0;
        out[2 * NTOK + tok * 2 + 1] = (float)i1;
        #pragma unroll
        for (int e = 0; e < NE; ++e) atomicAdd(&auxL[e], p[e] * inv);
        atomicAdd(&auxL[NE + i0], 1.f);
        atomicAdd(&auxL[NE + i1], 1.f);
    }

    __syncthreads();
    if (tid < 2 * NE) atomicAdd(&ws[tid], auxL[tid]);
}

// aux = E * sum(expert_frac * router_frac) * coef
__global__ void router_aux(const float* __restrict__ ws, float* __restrict__ out)
{
    if (threadIdx.x == 0 && blockIdx.x == 0) {
        float s = 0.f;
        #pragma unroll
        for (int e = 0; e < NE; ++e) {
            const float ef = ws[NE + e] / (float)(NTOK * 2);
            const float rf = ws[e] / (float)NTOK;
            s += ef * rf;
        }
        out[4 * NTOK] = (float)NE * s * AUX_COEF;
    }
}

extern "C" void kernel_launch(void* const* d_in, const int* in_sizes, int n_in,
                              void* d_out, int out_size, void* d_ws, size_t ws_size,
                              hipStream_t stream)
{
    const float* hs = (const float*)d_in[0];   // [4,4096,2048] f32
    const float* gw = (const float*)d_in[1];   // [8,2048] f32
    float* out = (float*)d_out;                // 32768 rw | 32768 idx | 1 aux
    float* ws  = (float*)d_ws;                 // 16 floats of accumulators

    const size_t lds_bytes = (GATE4 + NBUF * TPB * C4) * sizeof(float4); // 160 KB
    hipMemsetAsync(d_ws, 0, 2 * NE * sizeof(float), stream);
    hipLaunchKernelGGL(router_main, dim3(NTOK / TPB), dim3(512), lds_bytes,
                       stream, hs, gw, out, ws);
    hipLaunchKernelGGL(router_aux, dim3(1), dim3(64), 0, stream, ws, out);
}